// Round 5
// baseline (325.495 us; speedup 1.0000x reference)
//
#include <hip/hip_runtime.h>
#include <hip/hip_bf16.h>
#include <math.h>

#define TT 3
#define HH 96
#define WWD 96
#define CCH 128
#define NROWS (TT*HH*WWD)   // 27648

typedef __attribute__((ext_vector_type(8))) short short8;
typedef __attribute__((ext_vector_type(4))) float float4v;

__device__ __forceinline__ float bfu(unsigned short u){ union{unsigned u;float f;}c; c.u=((unsigned)u)<<16; return c.f; }
__device__ __forceinline__ unsigned short f2bf(float f){ __hip_bfloat16 h=__float2bfloat16(f); return *(unsigned short*)&h; }

// ---------------- Kernel 0: weight prep ----------------
__global__ void prep_kernel(const float* __restrict__ Wq, const float* __restrict__ Wk,
                            const float* __restrict__ Wv, const float* __restrict__ Wo,
                            unsigned short* __restrict__ Wt, unsigned short* __restrict__ Wo1,
                            unsigned short* __restrict__ Wo2) {
    int gid = blockIdx.x * 256 + threadIdx.x;
    int gsz = gridDim.x * 256;
    for (int e = gid; e < 3 * 16384; e += gsz) {
        int m = e >> 14, r = e & 16383, k = r >> 7, n = r & 127;
        const float* src = (m == 0) ? Wq : (m == 1) ? Wk : Wv;
        Wt[(size_t)(m * 128 + n) * 128 + k] = f2bf(src[k * 128 + n]);
    }
    for (int e = gid; e < 16384; e += gsz) {
        int k = e >> 7, n = e & 127;
        float wv = Wo[k * 128 + n];
        unsigned short w1 = f2bf(wv);
        Wo1[(size_t)n * 128 + k] = w1;
        Wo2[(size_t)n * 128 + k] = f2bf(wv - bfu(w1));
    }
}

// ---------------- Kernel 1: QKV projection, bf16 MFMA (swapped operands) ----------------
__launch_bounds__(256)
__global__ void qkv_kernel(const float* __restrict__ x,
                           const unsigned short* __restrict__ Wt,
                           const float* __restrict__ temp_emb,
                           const float* __restrict__ sp_emb,
                           unsigned short* __restrict__ Qb,
                           unsigned short* __restrict__ Kb,
                           unsigned short* __restrict__ Vb) {
    __shared__ unsigned short xs[32 * 136];
    const int tid = threadIdx.x;
    const int q0 = blockIdx.x * 32;
    for (int e = tid; e < 1024; e += 256) {
        int row = e >> 5, col = (e & 31) * 4;
        float4 v = *(const float4*)(x + (size_t)(q0 + row) * CCH + col);
        ushort4 u; u.x = f2bf(v.x); u.y = f2bf(v.y); u.z = f2bf(v.z); u.w = f2bf(v.w);
        *(ushort4*)&xs[row * 136 + col] = u;
    }
    __syncthreads();
    const int w = tid >> 6, lane = tid & 63, quad = lane >> 4, l16 = lane & 15;
    float4v acc[6][2];
#pragma unroll
    for (int mt = 0; mt < 6; ++mt) { acc[mt][0] = (float4v){0,0,0,0}; acc[mt][1] = (float4v){0,0,0,0}; }
#pragma unroll
    for (int ks = 0; ks < 4; ++ks) {
        short8 b0 = *(const short8*)&xs[l16 * 136 + ks * 32 + quad * 8];
        short8 b1 = *(const short8*)&xs[(16 + l16) * 136 + ks * 32 + quad * 8];
#pragma unroll
        for (int mt = 0; mt < 6; ++mt) {
            short8 a = *(const short8*)(Wt + (size_t)(w * 96 + mt * 16 + l16) * CCH + ks * 32 + quad * 8);
            acc[mt][0] = __builtin_amdgcn_mfma_f32_16x16x32_bf16(a, b0, acc[mt][0], 0, 0, 0);
            acc[mt][1] = __builtin_amdgcn_mfma_f32_16x16x32_bf16(a, b1, acc[mt][1], 0, 0, 0);
        }
    }
#pragma unroll
    for (int nt = 0; nt < 2; ++nt) {
        int q = q0 + nt * 16 + l16;
        int t = q / (HH * WWD); int rem = q - t * (HH * WWD);
        int yy = rem / WWD, xx = rem - (rem / WWD) * WWD;
        int qidx = (yy - min(max(yy, 2), 93) + 2) * 5 + (xx - min(max(xx, 2), 93) + 2);
#pragma unroll
        for (int mt = 0; mt < 6; ++mt) {
            int colc = w * 96 + mt * 16 + quad * 4;
            int mat = colc >> 7, colb = colc & 127;
            float4v a = acc[mt][nt];
            ushort4 u;
            if (mat == 0) {
                float4 te = *(const float4*)(temp_emb + t * CCH + colb);
                float4 se = *(const float4*)(sp_emb + qidx * CCH + colb);
                u.x = f2bf((a[0] + te.x + se.x) * 0.25f);
                u.y = f2bf((a[1] + te.y + se.y) * 0.25f);
                u.z = f2bf((a[2] + te.z + se.z) * 0.25f);
                u.w = f2bf((a[3] + te.w + se.w) * 0.25f);
                *(ushort4*)(Qb + (size_t)q * CCH + colb) = u;
            } else if (mat == 1) {
                float4 te = *(const float4*)(temp_emb + t * CCH + colb);
                u.x = f2bf(a[0] + te.x); u.y = f2bf(a[1] + te.y);
                u.z = f2bf(a[2] + te.z); u.w = f2bf(a[3] + te.w);
                *(ushort4*)(Kb + (size_t)q * CCH + colb) = u;
            } else {
                u.x = f2bf(a[0]); u.y = f2bf(a[1]); u.z = f2bf(a[2]); u.w = f2bf(a[3]);
                *(ushort4*)(Vb + (size_t)q * CCH + colb) = u;
            }
        }
    }
}

// ---------------- Kernel 2: per-thread online-softmax attention, wave-level key split ----------------
// Block = 4x2 query tile; 384 thr = 6 waves. lane = h(3b) | qx(2b) | qy(1b);
// wave w = tq + 3*s, s = key-split half (wave-uniform). Thread does keys
// kk = s, s+2, ... (13 slots, 13th of s=1 masked). Partials merged via LDS
// (aliased over the dead K/V tile) at the end. K/V staged bf16, y-major slots.
#define ATX 4
#define ATY 2
#define AHX 8
#define AHY 6
#define NSLOT 48
#define KSTR 136

__launch_bounds__(384, 5)
__global__ void attn_kernel(const unsigned short* Qb,
                            const unsigned short* __restrict__ Kb,
                            const unsigned short* __restrict__ Vb,
                            const float* __restrict__ sp_emb,
                            unsigned short* Ob) {
    __shared__ __align__(16) unsigned short KV[2 * NSLOT * KSTR];   // 25.5 KB
    unsigned short* Ks = KV;
    unsigned short* Vs = KV + NSLOT * KSTR;

    const int tid = threadIdx.x;
    const int lane = tid & 63;
    const int h = lane & 7, qx = (lane >> 3) & 3, qy = lane >> 5;
    const int w = tid >> 6;
    const int tq = w % 3, s = w / 3;

    const int bx = blockIdx.x % (WWD / ATX);
    const int by = blockIdx.x / (WWD / ATX);
    const int x0 = bx * ATX, y0 = by * ATY;
    const int xlo = min(min(max(x0, 2), 93) - 2, WWD - AHX);
    const int ylo = min(min(max(y0, 2), 93) - 2, HH - AHY);
    const int yy = y0 + qy, xx = x0 + qx;
    const int yc = min(max(yy, 2), 93), xc = min(max(xx, 2), 93);
    const int lyo = yc - 2 - ylo, lxo = xc - 2 - xlo;
    const int h16 = h * 16;
    const int qrow = tq * (HH * WWD) + yy * WWD + xx;

    // Q (bf16, pre-scaled by 1/sqrt(d) in qkv epilogue) -> 16 fp32
    float qv[16];
    {
        uint4 a = *(const uint4*)(Qb + (size_t)qrow * CCH + h16);
        uint4 b = *(const uint4*)(Qb + (size_t)qrow * CCH + h16 + 8);
        const unsigned short* pa = (const unsigned short*)&a;
        const unsigned short* pb = (const unsigned short*)&b;
#pragma unroll
        for (int j = 0; j < 8; ++j) { qv[j] = bfu(pa[j]); qv[8 + j] = bfu(pb[j]); }
    }

    // qsp[idx] = qv . sp_emb[kk]  for this thread's 13 keys
    float qsp[13];
#pragma unroll
    for (int idx = 0; idx < 13; ++idx) {
        int kk = s + 2 * idx;
        int kc = (kk < 25) ? kk : 24;
        const float4* sp = (const float4*)(sp_emb + kc * CCH + h16);
        float a0 = 0.f;
#pragma unroll
        for (int d4 = 0; d4 < 4; ++d4) {
            float4 f = sp[d4];
            a0 += qv[d4 * 4 + 0] * f.x + qv[d4 * 4 + 1] * f.y
                + qv[d4 * 4 + 2] * f.z + qv[d4 * 4 + 3] * f.w;
        }
        qsp[idx] = a0;
    }

    float m = -1e30f, l = 0.f;
    float acc[16];
#pragma unroll
    for (int d = 0; d < 16; ++d) acc[d] = 0.f;

    for (int t = 0; t < TT; ++t) {
        __syncthreads();
        // stage K/V halo (48 slots x 128 ch bf16), y-major slot = gxr*6 + gyr
        for (int e = tid; e < NSLOT * 16; e += 384) {
            int slot = e >> 4, c = e & 15;
            int gy = ylo + slot % 6;
            int gx = xlo + slot / 6;
            size_t g = ((size_t)(t * HH + gy) * WWD + gx) * CCH + c * 8;
            *(uint4*)&Ks[slot * KSTR + c * 8] = *(const uint4*)(Kb + g);
            *(uint4*)&Vs[slot * KSTR + c * 8] = *(const uint4*)(Vb + g);
        }
        __syncthreads();

        float sc[13];
#pragma unroll
        for (int idx = 0; idx < 13; ++idx) {
            int kk = s + 2 * idx;
            bool valid = kk < 25;
            int kc = valid ? kk : 24;
            int py = (kc * 205) >> 10, px = kc - py * 5;
            int base = ((lxo + px) * 6 + (lyo + py)) * KSTR + h16;
            uint4 ka = *(const uint4*)&Ks[base];
            uint4 kb = *(const uint4*)&Ks[base + 8];
            const unsigned short* p0 = (const unsigned short*)&ka;
            const unsigned short* p1 = (const unsigned short*)&kb;
            float a0 = 0.f, a1 = 0.f;
#pragma unroll
            for (int j = 0; j < 8; ++j) {
                a0 += qv[j] * bfu(p0[j]);
                a1 += qv[8 + j] * bfu(p1[j]);
            }
            sc[idx] = valid ? (a0 + a1 + qsp[idx]) : -1e30f;
        }

        float fm = m;
#pragma unroll
        for (int idx = 0; idx < 13; ++idx) fm = fmaxf(fm, sc[idx]);
        float corr = __expf(m - fm);
        m = fm; l *= corr;
#pragma unroll
        for (int d = 0; d < 16; ++d) acc[d] *= corr;

#pragma unroll
        for (int idx = 0; idx < 13; ++idx) {
            float wv = __expf(sc[idx] - m);
            l += wv;
            int kk = s + 2 * idx;
            int kc = (kk < 25) ? kk : 24;
            int py = (kc * 205) >> 10, px = kc - py * 5;
            int base = ((lxo + px) * 6 + (lyo + py)) * KSTR + h16;
            uint4 va = *(const uint4*)&Vs[base];
            uint4 vb = *(const uint4*)&Vs[base + 8];
            const unsigned short* p0 = (const unsigned short*)&va;
            const unsigned short* p1 = (const unsigned short*)&vb;
#pragma unroll
            for (int j = 0; j < 8; ++j) {
                acc[j]     += wv * bfu(p0[j]);
                acc[8 + j] += wv * bfu(p1[j]);
            }
        }
    }

    // merge the two key-split halves through LDS (aliased over dead K/V tile)
    __syncthreads();
    float* mb = (float*)KV;       // 192 pairs x 18 floats = 13.8 KB <= 25.5 KB
    int pair = tq * 64 + lane;
    if (s == 1) {
        float* p = mb + pair * 18;
#pragma unroll
        for (int d = 0; d < 16; ++d) p[d] = acc[d];
        p[16] = m; p[17] = l;
    }
    __syncthreads();
    if (s == 0) {
        const float* p = mb + pair * 18;
        float m1 = p[16], l1 = p[17];
        float M = fmaxf(m, m1);
        float c0 = __expf(m - M), c1 = __expf(m1 - M);
        float inv = 1.f / (l * c0 + l1 * c1);
        unsigned short ob[16];
#pragma unroll
        for (int d = 0; d < 16; ++d)
            ob[d] = f2bf((acc[d] * c0 + p[d] * c1) * inv);
        *(uint4*)(Ob + (size_t)qrow * CCH + h16)     = *(uint4*)&ob[0];
        *(uint4*)(Ob + (size_t)qrow * CCH + h16 + 8) = *(uint4*)&ob[8];
    }
}

// ---------------- Kernel 3: output projection, MFMA double-bf16 Wo + transpose scatter ----------------
__launch_bounds__(256)
__global__ void out_proj_kernel(const unsigned short* __restrict__ A,
                                const unsigned short* __restrict__ Wo1,
                                const unsigned short* __restrict__ Wo2,
                                float* __restrict__ out) {
    __shared__ unsigned short as[32 * 136];
    const int tid = threadIdx.x;
    const int q0 = blockIdx.x * 32;
    for (int e = tid; e < 512; e += 256) {
        int row = e >> 4, c = e & 15;
        *(uint4*)&as[row * 136 + c * 8] = *(const uint4*)(A + (size_t)(q0 + row) * CCH + c * 8);
    }
    __syncthreads();
    const int w = tid >> 6, lane = tid & 63, quad = lane >> 4, l16 = lane & 15;
    float4v acc[2][2];
#pragma unroll
    for (int mt = 0; mt < 2; ++mt) { acc[mt][0] = (float4v){0,0,0,0}; acc[mt][1] = (float4v){0,0,0,0}; }
#pragma unroll
    for (int ks = 0; ks < 4; ++ks) {
        short8 b0 = *(const short8*)&as[l16 * 136 + ks * 32 + quad * 8];
        short8 b1 = *(const short8*)&as[(16 + l16) * 136 + ks * 32 + quad * 8];
#pragma unroll
        for (int mt = 0; mt < 2; ++mt) {
            size_t wo = (size_t)(w * 32 + mt * 16 + l16) * CCH + ks * 32 + quad * 8;
            short8 a1 = *(const short8*)(Wo1 + wo);
            short8 a2 = *(const short8*)(Wo2 + wo);
            acc[mt][0] = __builtin_amdgcn_mfma_f32_16x16x32_bf16(a1, b0, acc[mt][0], 0, 0, 0);
            acc[mt][0] = __builtin_amdgcn_mfma_f32_16x16x32_bf16(a2, b0, acc[mt][0], 0, 0, 0);
            acc[mt][1] = __builtin_amdgcn_mfma_f32_16x16x32_bf16(a1, b1, acc[mt][1], 0, 0, 0);
            acc[mt][1] = __builtin_amdgcn_mfma_f32_16x16x32_bf16(a2, b1, acc[mt][1], 0, 0, 0);
        }
    }
#pragma unroll
    for (int nt = 0; nt < 2; ++nt) {
        int q = q0 + nt * 16 + l16;
        int t = q / (HH * WWD); int rem = q - t * (HH * WWD);
        int yy = rem / WWD, xx = rem - (rem / WWD) * WWD;
        size_t ob = ((size_t)(yy * WWD + xx) * TT + t) * CCH;
#pragma unroll
        for (int mt = 0; mt < 2; ++mt) {
            float4 o;
            o.x = acc[mt][nt][0]; o.y = acc[mt][nt][1];
            o.z = acc[mt][nt][2]; o.w = acc[mt][nt][3];
            *(float4*)(out + ob + w * 32 + mt * 16 + quad * 4) = o;
        }
    }
}

extern "C" void kernel_launch(void* const* d_in, const int* in_sizes, int n_in,
                              void* d_out, int out_size, void* d_ws, size_t ws_size,
                              hipStream_t stream) {
    const float* x        = (const float*)d_in[0];
    const float* Wq       = (const float*)d_in[1];
    const float* Wk       = (const float*)d_in[2];
    const float* Wv       = (const float*)d_in[3];
    const float* Wo       = (const float*)d_in[4];
    const float* temp_emb = (const float*)d_in[5];
    const float* sp_emb   = (const float*)d_in[6];
    float* out = (float*)d_out;

    const size_t nb = (size_t)NROWS * CCH * 2;   // bytes per bf16 buffer
    unsigned short* Qb  = (unsigned short*)d_ws;
    unsigned short* Kb  = (unsigned short*)((char*)d_ws + nb);
    unsigned short* Vb  = (unsigned short*)((char*)d_ws + 2 * nb);
    unsigned short* Wt  = (unsigned short*)((char*)d_ws + 3 * nb);
    unsigned short* Wo1 = Wt + 384 * 128;
    unsigned short* Wo2 = Wo1 + 128 * 128;

    prep_kernel<<<96, 256, 0, stream>>>(Wq, Wk, Wv, Wo, Wt, Wo1, Wo2);
    qkv_kernel<<<NROWS / 32, 256, 0, stream>>>(x, Wt, temp_emb, sp_emb, Qb, Kb, Vb);
    attn_kernel<<<(HH / ATY) * (WWD / ATX), 384, 0, stream>>>(Qb, Kb, Vb, sp_emb, Qb);
    out_proj_kernel<<<NROWS / 32, 256, 0, stream>>>(Qb, Wo1, Wo2, out);
}

// Round 6
// 210.493 us; speedup vs baseline: 1.5464x; 1.5464x over previous
//
#include <hip/hip_runtime.h>
#include <hip/hip_bf16.h>
#include <math.h>

#define TT 3
#define HH 96
#define WWD 96
#define CCH 128
#define NROWS (TT*HH*WWD)   // 27648

typedef __attribute__((ext_vector_type(8))) short short8;
typedef __attribute__((ext_vector_type(4))) float float4v;

__device__ __forceinline__ float bfu(unsigned short u){ union{unsigned u;float f;}c; c.u=((unsigned)u)<<16; return c.f; }
__device__ __forceinline__ unsigned short f2bf(float f){ __hip_bfloat16 h=__float2bfloat16(f); return *(unsigned short*)&h; }

// ---------------- Kernel 0: weight prep ----------------
__global__ void prep_kernel(const float* __restrict__ Wq, const float* __restrict__ Wk,
                            const float* __restrict__ Wv, const float* __restrict__ Wo,
                            unsigned short* __restrict__ Wt, unsigned short* __restrict__ Wo1,
                            unsigned short* __restrict__ Wo2) {
    int gid = blockIdx.x * 256 + threadIdx.x;
    int gsz = gridDim.x * 256;
    for (int e = gid; e < 3 * 16384; e += gsz) {
        int m = e >> 14, r = e & 16383, k = r >> 7, n = r & 127;
        const float* src = (m == 0) ? Wq : (m == 1) ? Wk : Wv;
        Wt[(size_t)(m * 128 + n) * 128 + k] = f2bf(src[k * 128 + n]);
    }
    for (int e = gid; e < 16384; e += gsz) {
        int k = e >> 7, n = e & 127;
        float wv = Wo[k * 128 + n];
        unsigned short w1 = f2bf(wv);
        Wo1[(size_t)n * 128 + k] = w1;
        Wo2[(size_t)n * 128 + k] = f2bf(wv - bfu(w1));
    }
}

// ---------------- Kernel 1: QKV projection, bf16 MFMA (swapped operands) ----------------
__launch_bounds__(256)
__global__ void qkv_kernel(const float* __restrict__ x,
                           const unsigned short* __restrict__ Wt,
                           const float* __restrict__ temp_emb,
                           const float* __restrict__ sp_emb,
                           unsigned short* __restrict__ Qb,
                           unsigned short* __restrict__ Kb,
                           unsigned short* __restrict__ Vb) {
    __shared__ unsigned short xs[32 * 136];
    const int tid = threadIdx.x;
    const int q0 = blockIdx.x * 32;
    for (int e = tid; e < 1024; e += 256) {
        int row = e >> 5, col = (e & 31) * 4;
        float4 v = *(const float4*)(x + (size_t)(q0 + row) * CCH + col);
        ushort4 u; u.x = f2bf(v.x); u.y = f2bf(v.y); u.z = f2bf(v.z); u.w = f2bf(v.w);
        *(ushort4*)&xs[row * 136 + col] = u;
    }
    __syncthreads();
    const int w = tid >> 6, lane = tid & 63, quad = lane >> 4, l16 = lane & 15;
    float4v acc[6][2];
#pragma unroll
    for (int mt = 0; mt < 6; ++mt) { acc[mt][0] = (float4v){0,0,0,0}; acc[mt][1] = (float4v){0,0,0,0}; }
#pragma unroll
    for (int ks = 0; ks < 4; ++ks) {
        short8 b0 = *(const short8*)&xs[l16 * 136 + ks * 32 + quad * 8];
        short8 b1 = *(const short8*)&xs[(16 + l16) * 136 + ks * 32 + quad * 8];
#pragma unroll
        for (int mt = 0; mt < 6; ++mt) {
            short8 a = *(const short8*)(Wt + (size_t)(w * 96 + mt * 16 + l16) * CCH + ks * 32 + quad * 8);
            acc[mt][0] = __builtin_amdgcn_mfma_f32_16x16x32_bf16(a, b0, acc[mt][0], 0, 0, 0);
            acc[mt][1] = __builtin_amdgcn_mfma_f32_16x16x32_bf16(a, b1, acc[mt][1], 0, 0, 0);
        }
    }
#pragma unroll
    for (int nt = 0; nt < 2; ++nt) {
        int q = q0 + nt * 16 + l16;
        int t = q / (HH * WWD); int rem = q - t * (HH * WWD);
        int yy = rem / WWD, xx = rem - (rem / WWD) * WWD;
        int qidx = (yy - min(max(yy, 2), 93) + 2) * 5 + (xx - min(max(xx, 2), 93) + 2);
#pragma unroll
        for (int mt = 0; mt < 6; ++mt) {
            int colc = w * 96 + mt * 16 + quad * 4;
            int mat = colc >> 7, colb = colc & 127;
            float4v a = acc[mt][nt];
            ushort4 u;
            if (mat == 0) {
                float4 te = *(const float4*)(temp_emb + t * CCH + colb);
                float4 se = *(const float4*)(sp_emb + qidx * CCH + colb);
                u.x = f2bf((a[0] + te.x + se.x) * 0.25f);
                u.y = f2bf((a[1] + te.y + se.y) * 0.25f);
                u.z = f2bf((a[2] + te.z + se.z) * 0.25f);
                u.w = f2bf((a[3] + te.w + se.w) * 0.25f);
                *(ushort4*)(Qb + (size_t)q * CCH + colb) = u;
            } else if (mat == 1) {
                float4 te = *(const float4*)(temp_emb + t * CCH + colb);
                u.x = f2bf(a[0] + te.x); u.y = f2bf(a[1] + te.y);
                u.z = f2bf(a[2] + te.z); u.w = f2bf(a[3] + te.w);
                *(ushort4*)(Kb + (size_t)q * CCH + colb) = u;
            } else {
                u.x = f2bf(a[0]); u.y = f2bf(a[1]); u.z = f2bf(a[2]); u.w = f2bf(a[3]);
                *(ushort4*)(Vb + (size_t)q * CCH + colb) = u;
            }
        }
    }
}

// ---------------- Kernel 2: per-thread online-softmax attention, wave-level key split ----------------
// Block = 4x2 query tile; 384 thr = 6 waves. lane = h(3b) | qx(2b) | qy(1b);
// wave w = tq + 3*s, s = key-split half (wave-uniform). Thread does keys
// kk = s, s+2, ... (13 slots, 13th of s=1 masked). Partials merged via LDS
// (aliased over the dead K/V tile) at the end. K/V staged bf16, y-major slots.
// NOTE: plain launch_bounds — R5's (384,5) forced VGPR=48 and spilled ~400 MB.
#define ATX 4
#define ATY 2
#define AHX 8
#define AHY 6
#define NSLOT 48
#define KSTR 136

__launch_bounds__(384)
__global__ void attn_kernel(const unsigned short* Qb,
                            const unsigned short* __restrict__ Kb,
                            const unsigned short* __restrict__ Vb,
                            const float* __restrict__ sp_emb,
                            unsigned short* Ob) {
    __shared__ __align__(16) unsigned short KV[2 * NSLOT * KSTR];   // 25.5 KB
    unsigned short* Ks = KV;
    unsigned short* Vs = KV + NSLOT * KSTR;

    const int tid = threadIdx.x;
    const int lane = tid & 63;
    const int h = lane & 7, qx = (lane >> 3) & 3, qy = lane >> 5;
    const int w = tid >> 6;
    const int tq = w % 3, s = w / 3;

    const int bx = blockIdx.x % (WWD / ATX);
    const int by = blockIdx.x / (WWD / ATX);
    const int x0 = bx * ATX, y0 = by * ATY;
    const int xlo = min(min(max(x0, 2), 93) - 2, WWD - AHX);
    const int ylo = min(min(max(y0, 2), 93) - 2, HH - AHY);
    const int yy = y0 + qy, xx = x0 + qx;
    const int yc = min(max(yy, 2), 93), xc = min(max(xx, 2), 93);
    const int lyo = yc - 2 - ylo, lxo = xc - 2 - xlo;
    const int h16 = h * 16;
    const int qrow = tq * (HH * WWD) + yy * WWD + xx;

    // Q (bf16, pre-scaled by 1/sqrt(d) in qkv epilogue) -> 16 fp32
    float qv[16];
    {
        uint4 a = *(const uint4*)(Qb + (size_t)qrow * CCH + h16);
        uint4 b = *(const uint4*)(Qb + (size_t)qrow * CCH + h16 + 8);
        const unsigned short* pa = (const unsigned short*)&a;
        const unsigned short* pb = (const unsigned short*)&b;
#pragma unroll
        for (int j = 0; j < 8; ++j) { qv[j] = bfu(pa[j]); qv[8 + j] = bfu(pb[j]); }
    }

    // qsp[idx] = qv . sp_emb[kk]  for this thread's 13 keys
    float qsp[13];
#pragma unroll
    for (int idx = 0; idx < 13; ++idx) {
        int kk = s + 2 * idx;
        int kc = (kk < 25) ? kk : 24;
        const float4* sp = (const float4*)(sp_emb + kc * CCH + h16);
        float a0 = 0.f;
#pragma unroll
        for (int d4 = 0; d4 < 4; ++d4) {
            float4 f = sp[d4];
            a0 += qv[d4 * 4 + 0] * f.x + qv[d4 * 4 + 1] * f.y
                + qv[d4 * 4 + 2] * f.z + qv[d4 * 4 + 3] * f.w;
        }
        qsp[idx] = a0;
    }

    float m = -1e30f, l = 0.f;
    float acc[16];
#pragma unroll
    for (int d = 0; d < 16; ++d) acc[d] = 0.f;

    for (int t = 0; t < TT; ++t) {
        __syncthreads();
        // stage K/V halo (48 slots x 128 ch bf16), y-major slot = gxr*6 + gyr
        for (int e = tid; e < NSLOT * 16; e += 384) {
            int slot = e >> 4, c = e & 15;
            int gy = ylo + slot % 6;
            int gx = xlo + slot / 6;
            size_t g = ((size_t)(t * HH + gy) * WWD + gx) * CCH + c * 8;
            *(uint4*)&Ks[slot * KSTR + c * 8] = *(const uint4*)(Kb + g);
            *(uint4*)&Vs[slot * KSTR + c * 8] = *(const uint4*)(Vb + g);
        }
        __syncthreads();

        float sc[13];
#pragma unroll
        for (int idx = 0; idx < 13; ++idx) {
            int kk = s + 2 * idx;
            bool valid = kk < 25;
            int kc = valid ? kk : 24;
            int py = (kc * 205) >> 10, px = kc - py * 5;
            int base = ((lxo + px) * 6 + (lyo + py)) * KSTR + h16;
            uint4 ka = *(const uint4*)&Ks[base];
            uint4 kb = *(const uint4*)&Ks[base + 8];
            const unsigned short* p0 = (const unsigned short*)&ka;
            const unsigned short* p1 = (const unsigned short*)&kb;
            float a0 = 0.f, a1 = 0.f;
#pragma unroll
            for (int j = 0; j < 8; ++j) {
                a0 += qv[j] * bfu(p0[j]);
                a1 += qv[8 + j] * bfu(p1[j]);
            }
            sc[idx] = valid ? (a0 + a1 + qsp[idx]) : -1e30f;
        }

        float fm = m;
#pragma unroll
        for (int idx = 0; idx < 13; ++idx) fm = fmaxf(fm, sc[idx]);
        float corr = __expf(m - fm);
        m = fm; l *= corr;
#pragma unroll
        for (int d = 0; d < 16; ++d) acc[d] *= corr;

#pragma unroll
        for (int idx = 0; idx < 13; ++idx) {
            float wv = __expf(sc[idx] - m);
            l += wv;
            int kk = s + 2 * idx;
            int kc = (kk < 25) ? kk : 24;
            int py = (kc * 205) >> 10, px = kc - py * 5;
            int base = ((lxo + px) * 6 + (lyo + py)) * KSTR + h16;
            uint4 va = *(const uint4*)&Vs[base];
            uint4 vb = *(const uint4*)&Vs[base + 8];
            const unsigned short* p0 = (const unsigned short*)&va;
            const unsigned short* p1 = (const unsigned short*)&vb;
#pragma unroll
            for (int j = 0; j < 8; ++j) {
                acc[j]     += wv * bfu(p0[j]);
                acc[8 + j] += wv * bfu(p1[j]);
            }
        }
    }

    // merge the two key-split halves through LDS (aliased over dead K/V tile)
    __syncthreads();
    float* mb = (float*)KV;       // 192 pairs x 18 floats = 13.8 KB <= 25.5 KB
    int pair = tq * 64 + lane;
    if (s == 1) {
        float* p = mb + pair * 18;
#pragma unroll
        for (int d = 0; d < 16; ++d) p[d] = acc[d];
        p[16] = m; p[17] = l;
    }
    __syncthreads();
    if (s == 0) {
        const float* p = mb + pair * 18;
        float m1 = p[16], l1 = p[17];
        float M = fmaxf(m, m1);
        float c0 = __expf(m - M), c1 = __expf(m1 - M);
        float inv = 1.f / (l * c0 + l1 * c1);
        unsigned short ob[16];
#pragma unroll
        for (int d = 0; d < 16; ++d)
            ob[d] = f2bf((acc[d] * c0 + p[d] * c1) * inv);
        *(uint4*)(Ob + (size_t)qrow * CCH + h16)     = *(uint4*)&ob[0];
        *(uint4*)(Ob + (size_t)qrow * CCH + h16 + 8) = *(uint4*)&ob[8];
    }
}

// ---------------- Kernel 3: output projection, MFMA double-bf16 Wo + transpose scatter ----------------
__launch_bounds__(256)
__global__ void out_proj_kernel(const unsigned short* __restrict__ A,
                                const unsigned short* __restrict__ Wo1,
                                const unsigned short* __restrict__ Wo2,
                                float* __restrict__ out) {
    __shared__ unsigned short as[32 * 136];
    const int tid = threadIdx.x;
    const int q0 = blockIdx.x * 32;
    for (int e = tid; e < 512; e += 256) {
        int row = e >> 4, c = e & 15;
        *(uint4*)&as[row * 136 + c * 8] = *(const uint4*)(A + (size_t)(q0 + row) * CCH + c * 8);
    }
    __syncthreads();
    const int w = tid >> 6, lane = tid & 63, quad = lane >> 4, l16 = lane & 15;
    float4v acc[2][2];
#pragma unroll
    for (int mt = 0; mt < 2; ++mt) { acc[mt][0] = (float4v){0,0,0,0}; acc[mt][1] = (float4v){0,0,0,0}; }
#pragma unroll
    for (int ks = 0; ks < 4; ++ks) {
        short8 b0 = *(const short8*)&as[l16 * 136 + ks * 32 + quad * 8];
        short8 b1 = *(const short8*)&as[(16 + l16) * 136 + ks * 32 + quad * 8];
#pragma unroll
        for (int mt = 0; mt < 2; ++mt) {
            size_t wo = (size_t)(w * 32 + mt * 16 + l16) * CCH + ks * 32 + quad * 8;
            short8 a1 = *(const short8*)(Wo1 + wo);
            short8 a2 = *(const short8*)(Wo2 + wo);
            acc[mt][0] = __builtin_amdgcn_mfma_f32_16x16x32_bf16(a1, b0, acc[mt][0], 0, 0, 0);
            acc[mt][0] = __builtin_amdgcn_mfma_f32_16x16x32_bf16(a2, b0, acc[mt][0], 0, 0, 0);
            acc[mt][1] = __builtin_amdgcn_mfma_f32_16x16x32_bf16(a1, b1, acc[mt][1], 0, 0, 0);
            acc[mt][1] = __builtin_amdgcn_mfma_f32_16x16x32_bf16(a2, b1, acc[mt][1], 0, 0, 0);
        }
    }
#pragma unroll
    for (int nt = 0; nt < 2; ++nt) {
        int q = q0 + nt * 16 + l16;
        int t = q / (HH * WWD); int rem = q - t * (HH * WWD);
        int yy = rem / WWD, xx = rem - (rem / WWD) * WWD;
        size_t ob = ((size_t)(yy * WWD + xx) * TT + t) * CCH;
#pragma unroll
        for (int mt = 0; mt < 2; ++mt) {
            float4 o;
            o.x = acc[mt][nt][0]; o.y = acc[mt][nt][1];
            o.z = acc[mt][nt][2]; o.w = acc[mt][nt][3];
            *(float4*)(out + ob + w * 32 + mt * 16 + quad * 4) = o;
        }
    }
}

extern "C" void kernel_launch(void* const* d_in, const int* in_sizes, int n_in,
                              void* d_out, int out_size, void* d_ws, size_t ws_size,
                              hipStream_t stream) {
    const float* x        = (const float*)d_in[0];
    const float* Wq       = (const float*)d_in[1];
    const float* Wk       = (const float*)d_in[2];
    const float* Wv       = (const float*)d_in[3];
    const float* Wo       = (const float*)d_in[4];
    const float* temp_emb = (const float*)d_in[5];
    const float* sp_emb   = (const float*)d_in[6];
    float* out = (float*)d_out;

    const size_t nb = (size_t)NROWS * CCH * 2;   // bytes per bf16 buffer
    unsigned short* Qb  = (unsigned short*)d_ws;
    unsigned short* Kb  = (unsigned short*)((char*)d_ws + nb);
    unsigned short* Vb  = (unsigned short*)((char*)d_ws + 2 * nb);
    unsigned short* Wt  = (unsigned short*)((char*)d_ws + 3 * nb);
    unsigned short* Wo1 = Wt + 384 * 128;
    unsigned short* Wo2 = Wo1 + 128 * 128;

    prep_kernel<<<96, 256, 0, stream>>>(Wq, Wk, Wv, Wo, Wt, Wo1, Wo2);
    qkv_kernel<<<NROWS / 32, 256, 0, stream>>>(x, Wt, temp_emb, sp_emb, Qb, Kb, Vb);
    attn_kernel<<<(HH / ATY) * (WWD / ATX), 384, 0, stream>>>(Qb, Kb, Vb, sp_emb, Qb);
    out_proj_kernel<<<NROWS / 32, 256, 0, stream>>>(Qb, Wo1, Wo2, out);
}

// Round 7
// 209.476 us; speedup vs baseline: 1.5539x; 1.0049x over previous
//
#include <hip/hip_runtime.h>
#include <hip/hip_bf16.h>
#include <math.h>

#define TT 3
#define HH 96
#define WWD 96
#define CCH 128
#define NROWS (TT*HH*WWD)   // 27648

typedef __attribute__((ext_vector_type(8))) short short8;
typedef __attribute__((ext_vector_type(4))) float float4v;

__device__ __forceinline__ float bfu(unsigned short u){ union{unsigned u;float f;}c; c.u=((unsigned)u)<<16; return c.f; }
__device__ __forceinline__ unsigned short f2bf(float f){ __hip_bfloat16 h=__float2bfloat16(f); return *(unsigned short*)&h; }

// ---------------- Kernel 0: weight prep ----------------
__global__ void prep_kernel(const float* __restrict__ Wq, const float* __restrict__ Wk,
                            const float* __restrict__ Wv, const float* __restrict__ Wo,
                            unsigned short* __restrict__ Wt, unsigned short* __restrict__ Wo1,
                            unsigned short* __restrict__ Wo2) {
    int gid = blockIdx.x * 256 + threadIdx.x;
    int gsz = gridDim.x * 256;
    for (int e = gid; e < 3 * 16384; e += gsz) {
        int m = e >> 14, r = e & 16383, k = r >> 7, n = r & 127;
        const float* src = (m == 0) ? Wq : (m == 1) ? Wk : Wv;
        Wt[(size_t)(m * 128 + n) * 128 + k] = f2bf(src[k * 128 + n]);
    }
    for (int e = gid; e < 16384; e += gsz) {
        int k = e >> 7, n = e & 127;
        float wv = Wo[k * 128 + n];
        unsigned short w1 = f2bf(wv);
        Wo1[(size_t)n * 128 + k] = w1;
        Wo2[(size_t)n * 128 + k] = f2bf(wv - bfu(w1));
    }
}

// ---------------- Kernel 1: QKV projection, bf16 MFMA (swapped operands) ----------------
__launch_bounds__(256)
__global__ void qkv_kernel(const float* __restrict__ x,
                           const unsigned short* __restrict__ Wt,
                           const float* __restrict__ temp_emb,
                           const float* __restrict__ sp_emb,
                           unsigned short* __restrict__ Qb,
                           unsigned short* __restrict__ Kb,
                           unsigned short* __restrict__ Vb) {
    __shared__ unsigned short xs[32 * 136];
    const int tid = threadIdx.x;
    const int q0 = blockIdx.x * 32;
    for (int e = tid; e < 1024; e += 256) {
        int row = e >> 5, col = (e & 31) * 4;
        float4 v = *(const float4*)(x + (size_t)(q0 + row) * CCH + col);
        ushort4 u; u.x = f2bf(v.x); u.y = f2bf(v.y); u.z = f2bf(v.z); u.w = f2bf(v.w);
        *(ushort4*)&xs[row * 136 + col] = u;
    }
    __syncthreads();
    const int w = tid >> 6, lane = tid & 63, quad = lane >> 4, l16 = lane & 15;
    float4v acc[6][2];
#pragma unroll
    for (int mt = 0; mt < 6; ++mt) { acc[mt][0] = (float4v){0,0,0,0}; acc[mt][1] = (float4v){0,0,0,0}; }
#pragma unroll
    for (int ks = 0; ks < 4; ++ks) {
        short8 b0 = *(const short8*)&xs[l16 * 136 + ks * 32 + quad * 8];
        short8 b1 = *(const short8*)&xs[(16 + l16) * 136 + ks * 32 + quad * 8];
#pragma unroll
        for (int mt = 0; mt < 6; ++mt) {
            short8 a = *(const short8*)(Wt + (size_t)(w * 96 + mt * 16 + l16) * CCH + ks * 32 + quad * 8);
            acc[mt][0] = __builtin_amdgcn_mfma_f32_16x16x32_bf16(a, b0, acc[mt][0], 0, 0, 0);
            acc[mt][1] = __builtin_amdgcn_mfma_f32_16x16x32_bf16(a, b1, acc[mt][1], 0, 0, 0);
        }
    }
#pragma unroll
    for (int nt = 0; nt < 2; ++nt) {
        int q = q0 + nt * 16 + l16;
        int t = q / (HH * WWD); int rem = q - t * (HH * WWD);
        int yy = rem / WWD, xx = rem - (rem / WWD) * WWD;
        int qidx = (yy - min(max(yy, 2), 93) + 2) * 5 + (xx - min(max(xx, 2), 93) + 2);
#pragma unroll
        for (int mt = 0; mt < 6; ++mt) {
            int colc = w * 96 + mt * 16 + quad * 4;
            int mat = colc >> 7, colb = colc & 127;
            float4v a = acc[mt][nt];
            ushort4 u;
            if (mat == 0) {
                float4 te = *(const float4*)(temp_emb + t * CCH + colb);
                float4 se = *(const float4*)(sp_emb + qidx * CCH + colb);
                u.x = f2bf((a[0] + te.x + se.x) * 0.25f);
                u.y = f2bf((a[1] + te.y + se.y) * 0.25f);
                u.z = f2bf((a[2] + te.z + se.z) * 0.25f);
                u.w = f2bf((a[3] + te.w + se.w) * 0.25f);
                *(ushort4*)(Qb + (size_t)q * CCH + colb) = u;
            } else if (mat == 1) {
                float4 te = *(const float4*)(temp_emb + t * CCH + colb);
                u.x = f2bf(a[0] + te.x); u.y = f2bf(a[1] + te.y);
                u.z = f2bf(a[2] + te.z); u.w = f2bf(a[3] + te.w);
                *(ushort4*)(Kb + (size_t)q * CCH + colb) = u;
            } else {
                u.x = f2bf(a[0]); u.y = f2bf(a[1]); u.z = f2bf(a[2]); u.w = f2bf(a[3]);
                *(ushort4*)(Vb + (size_t)q * CCH + colb) = u;
            }
        }
    }
}

// ---------------- Kernel 2: per-thread online-softmax attention ----------------
// R7: __launch_bounds__(384,3) (VGPR cap 170) + batched register prefetch (4 keys
// in flight) + frame-invariant LDS base addresses hoisted. Structure else = R6.
#define ATX 4
#define ATY 2
#define AHX 8
#define AHY 6
#define NSLOT 48
#define KSTR 136

__launch_bounds__(384, 3)
__global__ void attn_kernel(const unsigned short* Qb,
                            const unsigned short* __restrict__ Kb,
                            const unsigned short* __restrict__ Vb,
                            const float* __restrict__ sp_emb,
                            unsigned short* Ob) {
    __shared__ __align__(16) unsigned short KV[2 * NSLOT * KSTR];   // 25.5 KB
    unsigned short* Ks = KV;
    unsigned short* Vs = KV + NSLOT * KSTR;

    const int tid = threadIdx.x;
    const int lane = tid & 63;
    const int h = lane & 7, qx = (lane >> 3) & 3, qy = lane >> 5;
    const int w = tid >> 6;
    const int tq = w % 3, s = w / 3;

    const int bx = blockIdx.x % (WWD / ATX);
    const int by = blockIdx.x / (WWD / ATX);
    const int x0 = bx * ATX, y0 = by * ATY;
    const int xlo = min(min(max(x0, 2), 93) - 2, WWD - AHX);
    const int ylo = min(min(max(y0, 2), 93) - 2, HH - AHY);
    const int yy = y0 + qy, xx = x0 + qx;
    const int yc = min(max(yy, 2), 93), xc = min(max(xx, 2), 93);
    const int lyo = yc - 2 - ylo, lxo = xc - 2 - xlo;
    const int h16 = h * 16;
    const int qrow = tq * (HH * WWD) + yy * WWD + xx;

    // Q (bf16, pre-scaled by 1/sqrt(d) in qkv epilogue) -> 16 fp32
    float qv[16];
    {
        uint4 a = *(const uint4*)(Qb + (size_t)qrow * CCH + h16);
        uint4 b = *(const uint4*)(Qb + (size_t)qrow * CCH + h16 + 8);
        const unsigned short* pa = (const unsigned short*)&a;
        const unsigned short* pb = (const unsigned short*)&b;
#pragma unroll
        for (int j = 0; j < 8; ++j) { qv[j] = bfu(pa[j]); qv[8 + j] = bfu(pb[j]); }
    }

    // frame-invariant per-key LDS word bases (shorts)
    int kbase[13];
#pragma unroll
    for (int idx = 0; idx < 13; ++idx) {
        int kk = s + 2 * idx;
        int kc = (kk < 25) ? kk : 24;
        int py = (kc * 205) >> 10, px = kc - py * 5;
        kbase[idx] = ((lxo + px) * 6 + (lyo + py)) * KSTR + h16;
    }

    // qsp[idx] = qv . sp_emb[kk]
    float qsp[13];
#pragma unroll
    for (int idx = 0; idx < 13; ++idx) {
        int kk = s + 2 * idx;
        int kc = (kk < 25) ? kk : 24;
        const float4* sp = (const float4*)(sp_emb + kc * CCH + h16);
        float a0 = 0.f;
#pragma unroll
        for (int d4 = 0; d4 < 4; ++d4) {
            float4 f = sp[d4];
            a0 += qv[d4 * 4 + 0] * f.x + qv[d4 * 4 + 1] * f.y
                + qv[d4 * 4 + 2] * f.z + qv[d4 * 4 + 3] * f.w;
        }
        qsp[idx] = (s + 2 * idx < 25) ? a0 : -1e30f;   // fold validity into qsp
    }

    float m = -1e30f, l = 0.f;
    float acc[16];
#pragma unroll
    for (int d = 0; d < 16; ++d) acc[d] = 0.f;

    for (int t = 0; t < TT; ++t) {
        __syncthreads();
        for (int e = tid; e < NSLOT * 16; e += 384) {
            int slot = e >> 4, c = e & 15;
            int gy = ylo + slot % 6;
            int gx = xlo + slot / 6;
            size_t g = ((size_t)(t * HH + gy) * WWD + gx) * CCH + c * 8;
            *(uint4*)&Ks[slot * KSTR + c * 8] = *(const uint4*)(Kb + g);
            *(uint4*)&Vs[slot * KSTR + c * 8] = *(const uint4*)(Vb + g);
        }
        __syncthreads();

        float sc[13];
        // batched: load 4 keys' K-halves into regs, then compute their scores
#pragma unroll
        for (int b = 0; b < 13; b += 4) {
            uint4 ka[4], kb4[4];
#pragma unroll
            for (int j = 0; j < 4; ++j) {
                if (b + j < 13) {
                    ka[j]  = *(const uint4*)&Ks[kbase[b + j]];
                    kb4[j] = *(const uint4*)&Ks[kbase[b + j] + 8];
                }
            }
#pragma unroll
            for (int j = 0; j < 4; ++j) {
                if (b + j < 13) {
                    const unsigned short* p0 = (const unsigned short*)&ka[j];
                    const unsigned short* p1 = (const unsigned short*)&kb4[j];
                    float a0 = 0.f, a1 = 0.f;
#pragma unroll
                    for (int jj = 0; jj < 8; ++jj) {
                        a0 += qv[jj] * bfu(p0[jj]);
                        a1 += qv[8 + jj] * bfu(p1[jj]);
                    }
                    sc[b + j] = a0 + a1 + qsp[b + j];   // invalid keys: qsp = -1e30
                }
            }
        }

        float fm = m;
#pragma unroll
        for (int idx = 0; idx < 13; ++idx) fm = fmaxf(fm, sc[idx]);
        float corr = __expf(m - fm);
        m = fm; l *= corr;
#pragma unroll
        for (int d = 0; d < 16; ++d) acc[d] *= corr;

#pragma unroll
        for (int b = 0; b < 13; b += 4) {
            uint4 va[4], vb4[4];
#pragma unroll
            for (int j = 0; j < 4; ++j) {
                if (b + j < 13) {
                    va[j]  = *(const uint4*)&Vs[kbase[b + j]];
                    vb4[j] = *(const uint4*)&Vs[kbase[b + j] + 8];
                }
            }
#pragma unroll
            for (int j = 0; j < 4; ++j) {
                if (b + j < 13) {
                    float wv = __expf(sc[b + j] - m);
                    l += wv;
                    const unsigned short* p0 = (const unsigned short*)&va[j];
                    const unsigned short* p1 = (const unsigned short*)&vb4[j];
#pragma unroll
                    for (int jj = 0; jj < 8; ++jj) {
                        acc[jj]     += wv * bfu(p0[jj]);
                        acc[8 + jj] += wv * bfu(p1[jj]);
                    }
                }
            }
        }
    }

    // merge the two key-split halves through LDS (aliased over dead K/V tile)
    __syncthreads();
    float* mb = (float*)KV;       // 192 pairs x 18 floats = 13.8 KB <= 25.5 KB
    int pair = tq * 64 + lane;
    if (s == 1) {
        float* p = mb + pair * 18;
#pragma unroll
        for (int d = 0; d < 16; ++d) p[d] = acc[d];
        p[16] = m; p[17] = l;
    }
    __syncthreads();
    if (s == 0) {
        const float* p = mb + pair * 18;
        float m1 = p[16], l1 = p[17];
        float M = fmaxf(m, m1);
        float c0 = __expf(m - M), c1 = __expf(m1 - M);
        float inv = 1.f / (l * c0 + l1 * c1);
        unsigned short ob[16];
#pragma unroll
        for (int d = 0; d < 16; ++d)
            ob[d] = f2bf((acc[d] * c0 + p[d] * c1) * inv);
        *(uint4*)(Ob + (size_t)qrow * CCH + h16)     = *(uint4*)&ob[0];
        *(uint4*)(Ob + (size_t)qrow * CCH + h16 + 8) = *(uint4*)&ob[8];
    }
}

// ---------------- Kernel 3: output projection, MFMA double-bf16 Wo + transpose scatter ----------------
__launch_bounds__(256)
__global__ void out_proj_kernel(const unsigned short* __restrict__ A,
                                const unsigned short* __restrict__ Wo1,
                                const unsigned short* __restrict__ Wo2,
                                float* __restrict__ out) {
    __shared__ unsigned short as[32 * 136];
    const int tid = threadIdx.x;
    const int q0 = blockIdx.x * 32;
    for (int e = tid; e < 512; e += 256) {
        int row = e >> 4, c = e & 15;
        *(uint4*)&as[row * 136 + c * 8] = *(const uint4*)(A + (size_t)(q0 + row) * CCH + c * 8);
    }
    __syncthreads();
    const int w = tid >> 6, lane = tid & 63, quad = lane >> 4, l16 = lane & 15;
    float4v acc[2][2];
#pragma unroll
    for (int mt = 0; mt < 2; ++mt) { acc[mt][0] = (float4v){0,0,0,0}; acc[mt][1] = (float4v){0,0,0,0}; }
#pragma unroll
    for (int ks = 0; ks < 4; ++ks) {
        short8 b0 = *(const short8*)&as[l16 * 136 + ks * 32 + quad * 8];
        short8 b1 = *(const short8*)&as[(16 + l16) * 136 + ks * 32 + quad * 8];
#pragma unroll
        for (int mt = 0; mt < 2; ++mt) {
            size_t wo = (size_t)(w * 32 + mt * 16 + l16) * CCH + ks * 32 + quad * 8;
            short8 a1 = *(const short8*)(Wo1 + wo);
            short8 a2 = *(const short8*)(Wo2 + wo);
            acc[mt][0] = __builtin_amdgcn_mfma_f32_16x16x32_bf16(a1, b0, acc[mt][0], 0, 0, 0);
            acc[mt][0] = __builtin_amdgcn_mfma_f32_16x16x32_bf16(a2, b0, acc[mt][0], 0, 0, 0);
            acc[mt][1] = __builtin_amdgcn_mfma_f32_16x16x32_bf16(a1, b1, acc[mt][1], 0, 0, 0);
            acc[mt][1] = __builtin_amdgcn_mfma_f32_16x16x32_bf16(a2, b1, acc[mt][1], 0, 0, 0);
        }
    }
#pragma unroll
    for (int nt = 0; nt < 2; ++nt) {
        int q = q0 + nt * 16 + l16;
        int t = q / (HH * WWD); int rem = q - t * (HH * WWD);
        int yy = rem / WWD, xx = rem - (rem / WWD) * WWD;
        size_t ob = ((size_t)(yy * WWD + xx) * TT + t) * CCH;
#pragma unroll
        for (int mt = 0; mt < 2; ++mt) {
            float4 o;
            o.x = acc[mt][nt][0]; o.y = acc[mt][nt][1];
            o.z = acc[mt][nt][2]; o.w = acc[mt][nt][3];
            *(float4*)(out + ob + w * 32 + mt * 16 + quad * 4) = o;
        }
    }
}

extern "C" void kernel_launch(void* const* d_in, const int* in_sizes, int n_in,
                              void* d_out, int out_size, void* d_ws, size_t ws_size,
                              hipStream_t stream) {
    const float* x        = (const float*)d_in[0];
    const float* Wq       = (const float*)d_in[1];
    const float* Wk       = (const float*)d_in[2];
    const float* Wv       = (const float*)d_in[3];
    const float* Wo       = (const float*)d_in[4];
    const float* temp_emb = (const float*)d_in[5];
    const float* sp_emb   = (const float*)d_in[6];
    float* out = (float*)d_out;

    const size_t nb = (size_t)NROWS * CCH * 2;   // bytes per bf16 buffer
    unsigned short* Qb  = (unsigned short*)d_ws;
    unsigned short* Kb  = (unsigned short*)((char*)d_ws + nb);
    unsigned short* Vb  = (unsigned short*)((char*)d_ws + 2 * nb);
    unsigned short* Wt  = (unsigned short*)((char*)d_ws + 3 * nb);
    unsigned short* Wo1 = Wt + 384 * 128;
    unsigned short* Wo2 = Wo1 + 128 * 128;

    prep_kernel<<<96, 256, 0, stream>>>(Wq, Wk, Wv, Wo, Wt, Wo1, Wo2);
    qkv_kernel<<<NROWS / 32, 256, 0, stream>>>(x, Wt, temp_emb, sp_emb, Qb, Kb, Vb);
    attn_kernel<<<(HH / ATY) * (WWD / ATX), 384, 0, stream>>>(Qb, Kb, Vb, sp_emb, Qb);
    out_proj_kernel<<<NROWS / 32, 256, 0, stream>>>(Qb, Wo1, Wo2, out);
}

// Round 8
// 195.265 us; speedup vs baseline: 1.6669x; 1.0728x over previous
//
#include <hip/hip_runtime.h>
#include <hip/hip_bf16.h>
#include <math.h>

#define TT 3
#define HH 96
#define WWD 96
#define CCH 128
#define NROWS (TT*HH*WWD)   // 27648

typedef __attribute__((ext_vector_type(8))) short short8;
typedef __attribute__((ext_vector_type(4))) float float4v;

#if defined(__has_builtin)
#if __has_builtin(__builtin_amdgcn_fdot2_f32_bf16)
#define USE_DOT2 1
typedef __attribute__((ext_vector_type(2))) __bf16 bf2;
#endif
#endif

__device__ __forceinline__ float bfu(unsigned short u){ union{unsigned u;float f;}c; c.u=((unsigned)u)<<16; return c.f; }
__device__ __forceinline__ unsigned short f2bf(float f){ __hip_bfloat16 h=__float2bfloat16(f); return *(unsigned short*)&h; }

// ---------------- Kernel 0: weight prep ----------------
__global__ void prep_kernel(const float* __restrict__ Wq, const float* __restrict__ Wk,
                            const float* __restrict__ Wv, const float* __restrict__ Wo,
                            unsigned short* __restrict__ Wt, unsigned short* __restrict__ Wo1,
                            unsigned short* __restrict__ Wo2) {
    int gid = blockIdx.x * 256 + threadIdx.x;
    int gsz = gridDim.x * 256;
    for (int e = gid; e < 3 * 16384; e += gsz) {
        int m = e >> 14, r = e & 16383, k = r >> 7, n = r & 127;
        const float* src = (m == 0) ? Wq : (m == 1) ? Wk : Wv;
        Wt[(size_t)(m * 128 + n) * 128 + k] = f2bf(src[k * 128 + n]);
    }
    for (int e = gid; e < 16384; e += gsz) {
        int k = e >> 7, n = e & 127;
        float wv = Wo[k * 128 + n];
        unsigned short w1 = f2bf(wv);
        Wo1[(size_t)n * 128 + k] = w1;
        Wo2[(size_t)n * 128 + k] = f2bf(wv - bfu(w1));
    }
}

// ---------------- Kernel 1: QKV projection, bf16 MFMA, M-tile 64 ----------------
// Block 256 thr = 4 waves; 64 queries/block (4 nt groups); wave w covers concat
// cols [w*96, w*96+96). Halves Wt L2 re-reads vs M32; 24 MFMA per A-load pair.
__launch_bounds__(256)
__global__ void qkv_kernel(const float* __restrict__ x,
                           const unsigned short* __restrict__ Wt,
                           const float* __restrict__ temp_emb,
                           const float* __restrict__ sp_emb,
                           unsigned short* __restrict__ Qb,
                           unsigned short* __restrict__ Kb,
                           unsigned short* __restrict__ Vb) {
    __shared__ unsigned short xs[64 * 136];
    const int tid = threadIdx.x;
    const int q0 = blockIdx.x * 64;
    for (int e = tid; e < 2048; e += 256) {
        int row = e >> 5, col = (e & 31) * 4;
        float4 v = *(const float4*)(x + (size_t)(q0 + row) * CCH + col);
        ushort4 u; u.x = f2bf(v.x); u.y = f2bf(v.y); u.z = f2bf(v.z); u.w = f2bf(v.w);
        *(ushort4*)&xs[row * 136 + col] = u;
    }
    __syncthreads();
    const int w = tid >> 6, lane = tid & 63, quad = lane >> 4, l16 = lane & 15;
    float4v acc[6][4];
#pragma unroll
    for (int mt = 0; mt < 6; ++mt)
#pragma unroll
        for (int nt = 0; nt < 4; ++nt) acc[mt][nt] = (float4v){0,0,0,0};
#pragma unroll
    for (int ks = 0; ks < 4; ++ks) {
        short8 b[4];
#pragma unroll
        for (int nt = 0; nt < 4; ++nt)
            b[nt] = *(const short8*)&xs[(nt * 16 + l16) * 136 + ks * 32 + quad * 8];
#pragma unroll
        for (int mt = 0; mt < 6; ++mt) {
            short8 a = *(const short8*)(Wt + (size_t)(w * 96 + mt * 16 + l16) * CCH + ks * 32 + quad * 8);
#pragma unroll
            for (int nt = 0; nt < 4; ++nt)
                acc[mt][nt] = __builtin_amdgcn_mfma_f32_16x16x32_bf16(a, b[nt], acc[mt][nt], 0, 0, 0);
        }
    }
#pragma unroll
    for (int nt = 0; nt < 4; ++nt) {
        int q = q0 + nt * 16 + l16;
        int t = q / (HH * WWD); int rem = q - t * (HH * WWD);
        int yy = rem / WWD, xx = rem - (rem / WWD) * WWD;
        int qidx = (yy - min(max(yy, 2), 93) + 2) * 5 + (xx - min(max(xx, 2), 93) + 2);
#pragma unroll
        for (int mt = 0; mt < 6; ++mt) {
            int colc = w * 96 + mt * 16 + quad * 4;
            int mat = colc >> 7, colb = colc & 127;
            float4v a = acc[mt][nt];
            ushort4 u;
            if (mat == 0) {
                float4 te = *(const float4*)(temp_emb + t * CCH + colb);
                float4 se = *(const float4*)(sp_emb + qidx * CCH + colb);
                u.x = f2bf((a[0] + te.x + se.x) * 0.25f);
                u.y = f2bf((a[1] + te.y + se.y) * 0.25f);
                u.z = f2bf((a[2] + te.z + se.z) * 0.25f);
                u.w = f2bf((a[3] + te.w + se.w) * 0.25f);
                *(ushort4*)(Qb + (size_t)q * CCH + colb) = u;
            } else if (mat == 1) {
                float4 te = *(const float4*)(temp_emb + t * CCH + colb);
                u.x = f2bf(a[0] + te.x); u.y = f2bf(a[1] + te.y);
                u.z = f2bf(a[2] + te.z); u.w = f2bf(a[3] + te.w);
                *(ushort4*)(Kb + (size_t)q * CCH + colb) = u;
            } else {
                u.x = f2bf(a[0]); u.y = f2bf(a[1]); u.z = f2bf(a[2]); u.w = f2bf(a[3]);
                *(ushort4*)(Vb + (size_t)q * CCH + colb) = u;
            }
        }
    }
}

// ---------------- Kernel 2: per-thread online-softmax attention ----------------
// R8: score loop via v_dot2_f32_bf16 (Q stays packed bf16x2). Else = R7/R6.
#define ATX 4
#define ATY 2
#define AHX 8
#define AHY 6
#define NSLOT 48
#define KSTR 136

__launch_bounds__(384)
__global__ void attn_kernel(const unsigned short* Qb,
                            const unsigned short* __restrict__ Kb,
                            const unsigned short* __restrict__ Vb,
                            const float* __restrict__ sp_emb,
                            unsigned short* Ob) {
    __shared__ __align__(16) unsigned short KV[2 * NSLOT * KSTR];   // 25.5 KB
    unsigned short* Ks = KV;
    unsigned short* Vs = KV + NSLOT * KSTR;

    const int tid = threadIdx.x;
    const int lane = tid & 63;
    const int h = lane & 7, qx = (lane >> 3) & 3, qy = lane >> 5;
    const int w = tid >> 6;
    const int tq = w % 3, s = w / 3;

    const int bx = blockIdx.x % (WWD / ATX);
    const int by = blockIdx.x / (WWD / ATX);
    const int x0 = bx * ATX, y0 = by * ATY;
    const int xlo = min(min(max(x0, 2), 93) - 2, WWD - AHX);
    const int ylo = min(min(max(y0, 2), 93) - 2, HH - AHY);
    const int yy = y0 + qy, xx = x0 + qx;
    const int yc = min(max(yy, 2), 93), xc = min(max(xx, 2), 93);
    const int lyo = yc - 2 - ylo, lxo = xc - 2 - xlo;
    const int h16 = h * 16;
    const int qrow = tq * (HH * WWD) + yy * WWD + xx;

    // Q load (bf16, pre-scaled by 1/sqrt(d)): keep packed for dot2, unpack for qsp
    uint4 qa = *(const uint4*)(Qb + (size_t)qrow * CCH + h16);
    uint4 qb = *(const uint4*)(Qb + (size_t)qrow * CCH + h16 + 8);
    float qv[16];
    {
        const unsigned short* pa = (const unsigned short*)&qa;
        const unsigned short* pb = (const unsigned short*)&qb;
#pragma unroll
        for (int j = 0; j < 8; ++j) { qv[j] = bfu(pa[j]); qv[8 + j] = bfu(pb[j]); }
    }

    // frame-invariant per-key LDS word bases (shorts)
    int kbase[13];
#pragma unroll
    for (int idx = 0; idx < 13; ++idx) {
        int kk = s + 2 * idx;
        int kc = (kk < 25) ? kk : 24;
        int py = (kc * 205) >> 10, px = kc - py * 5;
        kbase[idx] = ((lxo + px) * 6 + (lyo + py)) * KSTR + h16;
    }

    // qsp[idx] = qv . sp_emb[kk]; invalid keys folded to -1e30
    float qsp[13];
#pragma unroll
    for (int idx = 0; idx < 13; ++idx) {
        int kk = s + 2 * idx;
        int kc = (kk < 25) ? kk : 24;
        const float4* sp = (const float4*)(sp_emb + kc * CCH + h16);
        float a0 = 0.f;
#pragma unroll
        for (int d4 = 0; d4 < 4; ++d4) {
            float4 f = sp[d4];
            a0 += qv[d4 * 4 + 0] * f.x + qv[d4 * 4 + 1] * f.y
                + qv[d4 * 4 + 2] * f.z + qv[d4 * 4 + 3] * f.w;
        }
        qsp[idx] = (kk < 25) ? a0 : -1e30f;
    }

#ifdef USE_DOT2
    bf2 qp2[8];
    {
        const bf2* pa = (const bf2*)&qa;
        const bf2* pb = (const bf2*)&qb;
#pragma unroll
        for (int j = 0; j < 4; ++j) { qp2[j] = pa[j]; qp2[4 + j] = pb[j]; }
    }
#endif

    float m = -1e30f, l = 0.f;
    float acc[16];
#pragma unroll
    for (int d = 0; d < 16; ++d) acc[d] = 0.f;

    for (int t = 0; t < TT; ++t) {
        __syncthreads();
        for (int e = tid; e < NSLOT * 16; e += 384) {
            int slot = e >> 4, c = e & 15;
            int gy = ylo + slot % 6;
            int gx = xlo + slot / 6;
            size_t g = ((size_t)(t * HH + gy) * WWD + gx) * CCH + c * 8;
            *(uint4*)&Ks[slot * KSTR + c * 8] = *(const uint4*)(Kb + g);
            *(uint4*)&Vs[slot * KSTR + c * 8] = *(const uint4*)(Vb + g);
        }
        __syncthreads();

        float sc[13];
#pragma unroll
        for (int b = 0; b < 13; b += 4) {
            uint4 ka[4], kb4[4];
#pragma unroll
            for (int j = 0; j < 4; ++j) {
                if (b + j < 13) {
                    ka[j]  = *(const uint4*)&Ks[kbase[b + j]];
                    kb4[j] = *(const uint4*)&Ks[kbase[b + j] + 8];
                }
            }
#pragma unroll
            for (int j = 0; j < 4; ++j) {
                if (b + j < 13) {
#ifdef USE_DOT2
                    const bf2* c0 = (const bf2*)&ka[j];
                    const bf2* c1 = (const bf2*)&kb4[j];
                    float t0 = qsp[b + j], t1 = 0.f;
#pragma unroll
                    for (int jj = 0; jj < 4; ++jj) {
                        t0 = __builtin_amdgcn_fdot2_f32_bf16(qp2[jj],     c0[jj], t0, false);
                        t1 = __builtin_amdgcn_fdot2_f32_bf16(qp2[4 + jj], c1[jj], t1, false);
                    }
                    sc[b + j] = t0 + t1;
#else
                    const unsigned short* p0 = (const unsigned short*)&ka[j];
                    const unsigned short* p1 = (const unsigned short*)&kb4[j];
                    float a0 = 0.f, a1 = 0.f;
#pragma unroll
                    for (int jj = 0; jj < 8; ++jj) {
                        a0 += qv[jj] * bfu(p0[jj]);
                        a1 += qv[8 + jj] * bfu(p1[jj]);
                    }
                    sc[b + j] = a0 + a1 + qsp[b + j];
#endif
                }
            }
        }

        float fm = m;
#pragma unroll
        for (int idx = 0; idx < 13; ++idx) fm = fmaxf(fm, sc[idx]);
        float corr = __expf(m - fm);
        m = fm; l *= corr;
#pragma unroll
        for (int d = 0; d < 16; ++d) acc[d] *= corr;

#pragma unroll
        for (int b = 0; b < 13; b += 4) {
            uint4 va[4], vb4[4];
#pragma unroll
            for (int j = 0; j < 4; ++j) {
                if (b + j < 13) {
                    va[j]  = *(const uint4*)&Vs[kbase[b + j]];
                    vb4[j] = *(const uint4*)&Vs[kbase[b + j] + 8];
                }
            }
#pragma unroll
            for (int j = 0; j < 4; ++j) {
                if (b + j < 13) {
                    float wv = __expf(sc[b + j] - m);
                    l += wv;
                    const unsigned short* p0 = (const unsigned short*)&va[j];
                    const unsigned short* p1 = (const unsigned short*)&vb4[j];
#pragma unroll
                    for (int jj = 0; jj < 8; ++jj) {
                        acc[jj]     += wv * bfu(p0[jj]);
                        acc[8 + jj] += wv * bfu(p1[jj]);
                    }
                }
            }
        }
    }

    // merge the two key-split halves through LDS (aliased over dead K/V tile)
    __syncthreads();
    float* mb = (float*)KV;       // 192 pairs x 18 floats = 13.8 KB <= 25.5 KB
    int pair = tq * 64 + lane;
    if (s == 1) {
        float* p = mb + pair * 18;
#pragma unroll
        for (int d = 0; d < 16; ++d) p[d] = acc[d];
        p[16] = m; p[17] = l;
    }
    __syncthreads();
    if (s == 0) {
        const float* p = mb + pair * 18;
        float m1 = p[16], l1 = p[17];
        float M = fmaxf(m, m1);
        float c0 = __expf(m - M), c1 = __expf(m1 - M);
        float inv = 1.f / (l * c0 + l1 * c1);
        unsigned short ob[16];
#pragma unroll
        for (int d = 0; d < 16; ++d)
            ob[d] = f2bf((acc[d] * c0 + p[d] * c1) * inv);
        *(uint4*)(Ob + (size_t)qrow * CCH + h16)     = *(uint4*)&ob[0];
        *(uint4*)(Ob + (size_t)qrow * CCH + h16 + 8) = *(uint4*)&ob[8];
    }
}

// ---------------- Kernel 3: output projection, MFMA double-bf16 Wo, M-tile 64 ----------------
__launch_bounds__(256)
__global__ void out_proj_kernel(const unsigned short* __restrict__ A,
                                const unsigned short* __restrict__ Wo1,
                                const unsigned short* __restrict__ Wo2,
                                float* __restrict__ out) {
    __shared__ unsigned short as[64 * 136];
    const int tid = threadIdx.x;
    const int q0 = blockIdx.x * 64;
    for (int e = tid; e < 1024; e += 256) {
        int row = e >> 4, c = e & 15;
        *(uint4*)&as[row * 136 + c * 8] = *(const uint4*)(A + (size_t)(q0 + row) * CCH + c * 8);
    }
    __syncthreads();
    const int w = tid >> 6, lane = tid & 63, quad = lane >> 4, l16 = lane & 15;
    float4v acc[2][4];
#pragma unroll
    for (int mt = 0; mt < 2; ++mt)
#pragma unroll
        for (int nt = 0; nt < 4; ++nt) acc[mt][nt] = (float4v){0,0,0,0};
#pragma unroll
    for (int ks = 0; ks < 4; ++ks) {
        short8 b[4];
#pragma unroll
        for (int nt = 0; nt < 4; ++nt)
            b[nt] = *(const short8*)&as[(nt * 16 + l16) * 136 + ks * 32 + quad * 8];
#pragma unroll
        for (int mt = 0; mt < 2; ++mt) {
            size_t wo = (size_t)(w * 32 + mt * 16 + l16) * CCH + ks * 32 + quad * 8;
            short8 a1 = *(const short8*)(Wo1 + wo);
            short8 a2 = *(const short8*)(Wo2 + wo);
#pragma unroll
            for (int nt = 0; nt < 4; ++nt) {
                acc[mt][nt] = __builtin_amdgcn_mfma_f32_16x16x32_bf16(a1, b[nt], acc[mt][nt], 0, 0, 0);
                acc[mt][nt] = __builtin_amdgcn_mfma_f32_16x16x32_bf16(a2, b[nt], acc[mt][nt], 0, 0, 0);
            }
        }
    }
#pragma unroll
    for (int nt = 0; nt < 4; ++nt) {
        int q = q0 + nt * 16 + l16;
        int t = q / (HH * WWD); int rem = q - t * (HH * WWD);
        int yy = rem / WWD, xx = rem - (rem / WWD) * WWD;
        size_t ob = ((size_t)(yy * WWD + xx) * TT + t) * CCH;
#pragma unroll
        for (int mt = 0; mt < 2; ++mt) {
            float4 o;
            o.x = acc[mt][nt][0]; o.y = acc[mt][nt][1];
            o.z = acc[mt][nt][2]; o.w = acc[mt][nt][3];
            *(float4*)(out + ob + w * 32 + mt * 16 + quad * 4) = o;
        }
    }
}

extern "C" void kernel_launch(void* const* d_in, const int* in_sizes, int n_in,
                              void* d_out, int out_size, void* d_ws, size_t ws_size,
                              hipStream_t stream) {
    const float* x        = (const float*)d_in[0];
    const float* Wq       = (const float*)d_in[1];
    const float* Wk       = (const float*)d_in[2];
    const float* Wv       = (const float*)d_in[3];
    const float* Wo       = (const float*)d_in[4];
    const float* temp_emb = (const float*)d_in[5];
    const float* sp_emb   = (const float*)d_in[6];
    float* out = (float*)d_out;

    const size_t nb = (size_t)NROWS * CCH * 2;   // bytes per bf16 buffer
    unsigned short* Qb  = (unsigned short*)d_ws;
    unsigned short* Kb  = (unsigned short*)((char*)d_ws + nb);
    unsigned short* Vb  = (unsigned short*)((char*)d_ws + 2 * nb);
    unsigned short* Wt  = (unsigned short*)((char*)d_ws + 3 * nb);
    unsigned short* Wo1 = Wt + 384 * 128;
    unsigned short* Wo2 = Wo1 + 128 * 128;

    prep_kernel<<<96, 256, 0, stream>>>(Wq, Wk, Wv, Wo, Wt, Wo1, Wo2);
    qkv_kernel<<<NROWS / 64, 256, 0, stream>>>(x, Wt, temp_emb, sp_emb, Qb, Kb, Vb);
    attn_kernel<<<(HH / ATY) * (WWD / ATX), 384, 0, stream>>>(Qb, Kb, Vb, sp_emb, Qb);
    out_proj_kernel<<<NROWS / 64, 256, 0, stream>>>(Qb, Wo1, Wo2, out);
}

// Round 9
// 172.089 us; speedup vs baseline: 1.8914x; 1.1347x over previous
//
#include <hip/hip_runtime.h>
#include <hip/hip_bf16.h>
#include <math.h>

#define TT 3
#define HH 96
#define WWD 96
#define CCH 128
#define NROWS (TT*HH*WWD)   // 27648

typedef __attribute__((ext_vector_type(8))) short short8;
typedef __attribute__((ext_vector_type(4))) float float4v;
typedef __attribute__((ext_vector_type(2))) float f32x2;

#if defined(__has_builtin)
#if __has_builtin(__builtin_amdgcn_fdot2_f32_bf16)
#define USE_DOT2 1
typedef __attribute__((ext_vector_type(2))) __bf16 bf2;
#endif
#endif

__device__ __forceinline__ float bfu(unsigned short u){ union{unsigned u;float f;}c; c.u=((unsigned)u)<<16; return c.f; }
__device__ __forceinline__ float bflo(unsigned u){ union{unsigned u;float f;}c; c.u=u<<16; return c.f; }
__device__ __forceinline__ float bfhi(unsigned u){ union{unsigned u;float f;}c; c.u=u&0xffff0000u; return c.f; }
__device__ __forceinline__ unsigned short f2bf(float f){ __hip_bfloat16 h=__float2bfloat16(f); return *(unsigned short*)&h; }

// ---------------- Kernel 0: weight prep, LDS-tile transpose (coalesced both sides) ----------------
// 64 blocks: b>>4 = matrix (0 Wq, 1 Wk, 2 Wv, 3 Wo), b&15 = 32x32 tile.
__launch_bounds__(256)
__global__ void prep_kernel(const float* __restrict__ Wq, const float* __restrict__ Wk,
                            const float* __restrict__ Wv, const float* __restrict__ Wo,
                            unsigned short* __restrict__ Wt, unsigned short* __restrict__ Wo1,
                            unsigned short* __restrict__ Wo2) {
    __shared__ float ts[32][33];
    const int m = blockIdx.x >> 4, tile = blockIdx.x & 15;
    const int k0 = (tile >> 2) * 32, n0 = (tile & 3) * 32;
    const float* src = (m == 0) ? Wq : (m == 1) ? Wk : (m == 2) ? Wv : Wo;
    const int tid = threadIdx.x;
    const int c = tid & 31, r8 = tid >> 5;
#pragma unroll
    for (int rr = 0; rr < 4; ++rr) {
        int r = r8 * 4 + rr;
        ts[r][c] = src[(size_t)(k0 + r) * 128 + n0 + c];
    }
    __syncthreads();
    // write transposed: row n0+r, cols k0+c (k-contiguous)
#pragma unroll
    for (int rr = 0; rr < 4; ++rr) {
        int r = r8 * 4 + rr;
        float v = ts[c][r];
        if (m < 3) {
            Wt[(size_t)(m * 128 + n0 + r) * 128 + k0 + c] = f2bf(v);
        } else {
            unsigned short w1 = f2bf(v);
            Wo1[(size_t)(n0 + r) * 128 + k0 + c] = w1;
            Wo2[(size_t)(n0 + r) * 128 + k0 + c] = f2bf(v - bfu(w1));
        }
    }
}

// ---------------- Kernel 1: QKV projection, bf16 MFMA, M-tile 64 ----------------
__launch_bounds__(256)
__global__ void qkv_kernel(const float* __restrict__ x,
                           const unsigned short* __restrict__ Wt,
                           const float* __restrict__ temp_emb,
                           const float* __restrict__ sp_emb,
                           unsigned short* __restrict__ Qb,
                           unsigned short* __restrict__ Kb,
                           unsigned short* __restrict__ Vb) {
    __shared__ unsigned short xs[64 * 136];
    const int tid = threadIdx.x;
    const int q0 = blockIdx.x * 64;
    for (int e = tid; e < 2048; e += 256) {
        int row = e >> 5, col = (e & 31) * 4;
        float4 v = *(const float4*)(x + (size_t)(q0 + row) * CCH + col);
        ushort4 u; u.x = f2bf(v.x); u.y = f2bf(v.y); u.z = f2bf(v.z); u.w = f2bf(v.w);
        *(ushort4*)&xs[row * 136 + col] = u;
    }
    __syncthreads();
    const int w = tid >> 6, lane = tid & 63, quad = lane >> 4, l16 = lane & 15;
    float4v acc[6][4];
#pragma unroll
    for (int mt = 0; mt < 6; ++mt)
#pragma unroll
        for (int nt = 0; nt < 4; ++nt) acc[mt][nt] = (float4v){0,0,0,0};
#pragma unroll
    for (int ks = 0; ks < 4; ++ks) {
        short8 b[4];
#pragma unroll
        for (int nt = 0; nt < 4; ++nt)
            b[nt] = *(const short8*)&xs[(nt * 16 + l16) * 136 + ks * 32 + quad * 8];
#pragma unroll
        for (int mt = 0; mt < 6; ++mt) {
            short8 a = *(const short8*)(Wt + (size_t)(w * 96 + mt * 16 + l16) * CCH + ks * 32 + quad * 8);
#pragma unroll
            for (int nt = 0; nt < 4; ++nt)
                acc[mt][nt] = __builtin_amdgcn_mfma_f32_16x16x32_bf16(a, b[nt], acc[mt][nt], 0, 0, 0);
        }
    }
#pragma unroll
    for (int nt = 0; nt < 4; ++nt) {
        int q = q0 + nt * 16 + l16;
        int t = q / (HH * WWD); int rem = q - t * (HH * WWD);
        int yy = rem / WWD, xx = rem - (rem / WWD) * WWD;
        int qidx = (yy - min(max(yy, 2), 93) + 2) * 5 + (xx - min(max(xx, 2), 93) + 2);
#pragma unroll
        for (int mt = 0; mt < 6; ++mt) {
            int colc = w * 96 + mt * 16 + quad * 4;
            int mat = colc >> 7, colb = colc & 127;
            float4v a = acc[mt][nt];
            ushort4 u;
            if (mat == 0) {
                float4 te = *(const float4*)(temp_emb + t * CCH + colb);
                float4 se = *(const float4*)(sp_emb + qidx * CCH + colb);
                u.x = f2bf((a[0] + te.x + se.x) * 0.25f);
                u.y = f2bf((a[1] + te.y + se.y) * 0.25f);
                u.z = f2bf((a[2] + te.z + se.z) * 0.25f);
                u.w = f2bf((a[3] + te.w + se.w) * 0.25f);
                *(ushort4*)(Qb + (size_t)q * CCH + colb) = u;
            } else if (mat == 1) {
                float4 te = *(const float4*)(temp_emb + t * CCH + colb);
                u.x = f2bf(a[0] + te.x); u.y = f2bf(a[1] + te.y);
                u.z = f2bf(a[2] + te.z); u.w = f2bf(a[3] + te.w);
                *(ushort4*)(Kb + (size_t)q * CCH + colb) = u;
            } else {
                u.x = f2bf(a[0]); u.y = f2bf(a[1]); u.z = f2bf(a[2]); u.w = f2bf(a[3]);
                *(ushort4*)(Vb + (size_t)q * CCH + colb) = u;
            }
        }
    }
}

// ---------------- Kernel 2: per-thread online-softmax attention ----------------
// R9: lane remap  lane = h(0-2) | qy(3) | qx(4-5)  -> first half-wave spans all
// 32 banks (was 16).  PV/rescale in f32x2 (v_pk_fma_f32).  Else = R8.
#define ATX 4
#define ATY 2
#define AHX 8
#define AHY 6
#define NSLOT 48
#define KSTR 136

__launch_bounds__(384)
__global__ void attn_kernel(const unsigned short* Qb,
                            const unsigned short* __restrict__ Kb,
                            const unsigned short* __restrict__ Vb,
                            const float* __restrict__ sp_emb,
                            unsigned short* Ob) {
    __shared__ __align__(16) unsigned short KV[2 * NSLOT * KSTR];   // 25.5 KB
    unsigned short* Ks = KV;
    unsigned short* Vs = KV + NSLOT * KSTR;

    const int tid = threadIdx.x;
    const int lane = tid & 63;
    const int h = lane & 7, qy = (lane >> 3) & 1, qx = (lane >> 4) & 3;
    const int w = tid >> 6;
    const int tq = w % 3, s = w / 3;

    const int bx = blockIdx.x % (WWD / ATX);
    const int by = blockIdx.x / (WWD / ATX);
    const int x0 = bx * ATX, y0 = by * ATY;
    const int xlo = min(min(max(x0, 2), 93) - 2, WWD - AHX);
    const int ylo = min(min(max(y0, 2), 93) - 2, HH - AHY);
    const int yy = y0 + qy, xx = x0 + qx;
    const int yc = min(max(yy, 2), 93), xc = min(max(xx, 2), 93);
    const int lyo = yc - 2 - ylo, lxo = xc - 2 - xlo;
    const int h16 = h * 16;
    const int qrow = tq * (HH * WWD) + yy * WWD + xx;

    uint4 qa = *(const uint4*)(Qb + (size_t)qrow * CCH + h16);
    uint4 qb = *(const uint4*)(Qb + (size_t)qrow * CCH + h16 + 8);
    float qv[16];
    {
        const unsigned short* pa = (const unsigned short*)&qa;
        const unsigned short* pb = (const unsigned short*)&qb;
#pragma unroll
        for (int j = 0; j < 8; ++j) { qv[j] = bfu(pa[j]); qv[8 + j] = bfu(pb[j]); }
    }

    int kbase[13];
#pragma unroll
    for (int idx = 0; idx < 13; ++idx) {
        int kk = s + 2 * idx;
        int kc = (kk < 25) ? kk : 24;
        int py = (kc * 205) >> 10, px = kc - py * 5;
        kbase[idx] = ((lxo + px) * 6 + (lyo + py)) * KSTR + h16;
    }

    float qsp[13];
#pragma unroll
    for (int idx = 0; idx < 13; ++idx) {
        int kk = s + 2 * idx;
        int kc = (kk < 25) ? kk : 24;
        const float4* sp = (const float4*)(sp_emb + kc * CCH + h16);
        float a0 = 0.f;
#pragma unroll
        for (int d4 = 0; d4 < 4; ++d4) {
            float4 f = sp[d4];
            a0 += qv[d4 * 4 + 0] * f.x + qv[d4 * 4 + 1] * f.y
                + qv[d4 * 4 + 2] * f.z + qv[d4 * 4 + 3] * f.w;
        }
        qsp[idx] = (kk < 25) ? a0 : -1e30f;
    }

#ifdef USE_DOT2
    bf2 qp2[8];
    {
        const bf2* pa = (const bf2*)&qa;
        const bf2* pb = (const bf2*)&qb;
#pragma unroll
        for (int j = 0; j < 4; ++j) { qp2[j] = pa[j]; qp2[4 + j] = pb[j]; }
    }
#endif

    float m = -1e30f, l = 0.f;
    f32x2 acc2[8];
#pragma unroll
    for (int d = 0; d < 8; ++d) acc2[d] = (f32x2){0.f, 0.f};

    for (int t = 0; t < TT; ++t) {
        __syncthreads();
        for (int e = tid; e < NSLOT * 16; e += 384) {
            int slot = e >> 4, c = e & 15;
            int gy = ylo + slot % 6;
            int gx = xlo + slot / 6;
            size_t g = ((size_t)(t * HH + gy) * WWD + gx) * CCH + c * 8;
            *(uint4*)&Ks[slot * KSTR + c * 8] = *(const uint4*)(Kb + g);
            *(uint4*)&Vs[slot * KSTR + c * 8] = *(const uint4*)(Vb + g);
        }
        __syncthreads();

        float sc[13];
#pragma unroll
        for (int b = 0; b < 13; b += 4) {
            uint4 ka[4], kb4[4];
#pragma unroll
            for (int j = 0; j < 4; ++j) {
                if (b + j < 13) {
                    ka[j]  = *(const uint4*)&Ks[kbase[b + j]];
                    kb4[j] = *(const uint4*)&Ks[kbase[b + j] + 8];
                }
            }
#pragma unroll
            for (int j = 0; j < 4; ++j) {
                if (b + j < 13) {
#ifdef USE_DOT2
                    const bf2* c0 = (const bf2*)&ka[j];
                    const bf2* c1 = (const bf2*)&kb4[j];
                    float t0 = qsp[b + j], t1 = 0.f;
#pragma unroll
                    for (int jj = 0; jj < 4; ++jj) {
                        t0 = __builtin_amdgcn_fdot2_f32_bf16(qp2[jj],     c0[jj], t0, false);
                        t1 = __builtin_amdgcn_fdot2_f32_bf16(qp2[4 + jj], c1[jj], t1, false);
                    }
                    sc[b + j] = t0 + t1;
#else
                    const unsigned short* p0 = (const unsigned short*)&ka[j];
                    const unsigned short* p1 = (const unsigned short*)&kb4[j];
                    float a0 = 0.f, a1 = 0.f;
#pragma unroll
                    for (int jj = 0; jj < 8; ++jj) {
                        a0 += qv[jj] * bfu(p0[jj]);
                        a1 += qv[8 + jj] * bfu(p1[jj]);
                    }
                    sc[b + j] = a0 + a1 + qsp[b + j];
#endif
                }
            }
        }

        float fm = m;
#pragma unroll
        for (int idx = 0; idx < 13; ++idx) fm = fmaxf(fm, sc[idx]);
        float corr = __expf(m - fm);
        m = fm; l *= corr;
        f32x2 corr2 = (f32x2){corr, corr};
#pragma unroll
        for (int d = 0; d < 8; ++d) acc2[d] *= corr2;

#pragma unroll
        for (int b = 0; b < 13; b += 4) {
            uint4 va[4], vb4[4];
#pragma unroll
            for (int j = 0; j < 4; ++j) {
                if (b + j < 13) {
                    va[j]  = *(const uint4*)&Vs[kbase[b + j]];
                    vb4[j] = *(const uint4*)&Vs[kbase[b + j] + 8];
                }
            }
#pragma unroll
            for (int j = 0; j < 4; ++j) {
                if (b + j < 13) {
                    float wv = __expf(sc[b + j] - m);
                    l += wv;
                    f32x2 wv2 = (f32x2){wv, wv};
                    const unsigned* u0 = (const unsigned*)&va[j];
                    const unsigned* u1 = (const unsigned*)&vb4[j];
#pragma unroll
                    for (int jj = 0; jj < 4; ++jj) {
                        f32x2 v0; v0.x = bflo(u0[jj]); v0.y = bfhi(u0[jj]);
                        f32x2 v1; v1.x = bflo(u1[jj]); v1.y = bfhi(u1[jj]);
                        acc2[jj]     += wv2 * v0;
                        acc2[4 + jj] += wv2 * v1;
                    }
                }
            }
        }
    }

    // merge the two key-split halves through LDS (aliased over dead K/V tile)
    __syncthreads();
    float* mb = (float*)KV;       // 192 pairs x 18 floats = 13.8 KB <= 25.5 KB
    int pair = tq * 64 + lane;
    const float* accf = (const float*)acc2;
    if (s == 1) {
        float* p = mb + pair * 18;
#pragma unroll
        for (int d = 0; d < 16; ++d) p[d] = accf[d];
        p[16] = m; p[17] = l;
    }
    __syncthreads();
    if (s == 0) {
        const float* p = mb + pair * 18;
        float m1 = p[16], l1 = p[17];
        float M = fmaxf(m, m1);
        float c0 = __expf(m - M), c1 = __expf(m1 - M);
        float inv = 1.f / (l * c0 + l1 * c1);
        unsigned short ob[16];
#pragma unroll
        for (int d = 0; d < 16; ++d)
            ob[d] = f2bf((accf[d] * c0 + p[d] * c1) * inv);
        *(uint4*)(Ob + (size_t)qrow * CCH + h16)     = *(uint4*)&ob[0];
        *(uint4*)(Ob + (size_t)qrow * CCH + h16 + 8) = *(uint4*)&ob[8];
    }
}

// ---------------- Kernel 3: output projection, MFMA double-bf16 Wo, M-tile 64 ----------------
__launch_bounds__(256)
__global__ void out_proj_kernel(const unsigned short* __restrict__ A,
                                const unsigned short* __restrict__ Wo1,
                                const unsigned short* __restrict__ Wo2,
                                float* __restrict__ out) {
    __shared__ unsigned short as[64 * 136];
    const int tid = threadIdx.x;
    const int q0 = blockIdx.x * 64;
    for (int e = tid; e < 1024; e += 256) {
        int row = e >> 4, c = e & 15;
        *(uint4*)&as[row * 136 + c * 8] = *(const uint4*)(A + (size_t)(q0 + row) * CCH + c * 8);
    }
    __syncthreads();
    const int w = tid >> 6, lane = tid & 63, quad = lane >> 4, l16 = lane & 15;
    float4v acc[2][4];
#pragma unroll
    for (int mt = 0; mt < 2; ++mt)
#pragma unroll
        for (int nt = 0; nt < 4; ++nt) acc[mt][nt] = (float4v){0,0,0,0};
#pragma unroll
    for (int ks = 0; ks < 4; ++ks) {
        short8 b[4];
#pragma unroll
        for (int nt = 0; nt < 4; ++nt)
            b[nt] = *(const short8*)&as[(nt * 16 + l16) * 136 + ks * 32 + quad * 8];
#pragma unroll
        for (int mt = 0; mt < 2; ++mt) {
            size_t wo = (size_t)(w * 32 + mt * 16 + l16) * CCH + ks * 32 + quad * 8;
            short8 a1 = *(const short8*)(Wo1 + wo);
            short8 a2 = *(const short8*)(Wo2 + wo);
#pragma unroll
            for (int nt = 0; nt < 4; ++nt) {
                acc[mt][nt] = __builtin_amdgcn_mfma_f32_16x16x32_bf16(a1, b[nt], acc[mt][nt], 0, 0, 0);
                acc[mt][nt] = __builtin_amdgcn_mfma_f32_16x16x32_bf16(a2, b[nt], acc[mt][nt], 0, 0, 0);
            }
        }
    }
#pragma unroll
    for (int nt = 0; nt < 4; ++nt) {
        int q = q0 + nt * 16 + l16;
        int t = q / (HH * WWD); int rem = q - t * (HH * WWD);
        int yy = rem / WWD, xx = rem - (rem / WWD) * WWD;
        size_t ob = ((size_t)(yy * WWD + xx) * TT + t) * CCH;
#pragma unroll
        for (int mt = 0; mt < 2; ++mt) {
            float4 o;
            o.x = acc[mt][nt][0]; o.y = acc[mt][nt][1];
            o.z = acc[mt][nt][2]; o.w = acc[mt][nt][3];
            *(float4*)(out + ob + w * 32 + mt * 16 + quad * 4) = o;
        }
    }
}

extern "C" void kernel_launch(void* const* d_in, const int* in_sizes, int n_in,
                              void* d_out, int out_size, void* d_ws, size_t ws_size,
                              hipStream_t stream) {
    const float* x        = (const float*)d_in[0];
    const float* Wq       = (const float*)d_in[1];
    const float* Wk       = (const float*)d_in[2];
    const float* Wv       = (const float*)d_in[3];
    const float* Wo       = (const float*)d_in[4];
    const float* temp_emb = (const float*)d_in[5];
    const float* sp_emb   = (const float*)d_in[6];
    float* out = (float*)d_out;

    const size_t nb = (size_t)NROWS * CCH * 2;   // bytes per bf16 buffer
    unsigned short* Qb  = (unsigned short*)d_ws;
    unsigned short* Kb  = (unsigned short*)((char*)d_ws + nb);
    unsigned short* Vb  = (unsigned short*)((char*)d_ws + 2 * nb);
    unsigned short* Wt  = (unsigned short*)((char*)d_ws + 3 * nb);
    unsigned short* Wo1 = Wt + 384 * 128;
    unsigned short* Wo2 = Wo1 + 128 * 128;

    prep_kernel<<<64, 256, 0, stream>>>(Wq, Wk, Wv, Wo, Wt, Wo1, Wo2);
    qkv_kernel<<<NROWS / 64, 256, 0, stream>>>(x, Wt, temp_emb, sp_emb, Qb, Kb, Vb);
    attn_kernel<<<(HH / ATY) * (WWD / ATX), 384, 0, stream>>>(Qb, Kb, Vb, sp_emb, Qb);
    out_proj_kernel<<<NROWS / 64, 256, 0, stream>>>(Qb, Wo1, Wo2, out);
}